// Round 1
// 246.008 us; speedup vs baseline: 1.0851x; 1.0851x over previous
//
#include <hip/hip_runtime.h>
#include <hip/hip_bf16.h>

// MultiheadAttention: B=2, S=2048, D=1024, H=16, dk=64.
// Inputs fp32, output fp32. Internals bf16 MFMA.
// V is produced TRANSPOSED ([feature][token]) by its projection GEMM, with
// tokens PERMUTED within each 64-token tile (t=c*16+g*4+e -> g*16+c*4+e) so
// the attention PV B-operand is a single contiguous b128 LDS read.
// All LDS tiles use stride-64 rows with XOR swizzle col ^= ((row&7)<<3)
// (16B granule) -> conflict-free ds_read_b128 / uint4 writes.
// Attention: QBLK=32 q-rows per wave (2 q-subtiles share every K/Vt fragment
// read) to double MFMA per LDS byte. P stays in registers (S^T orientation).

typedef __attribute__((ext_vector_type(8))) short short8;   // 8 bf16 = 4 VGPR (MFMA A/B frag)
typedef __attribute__((ext_vector_type(4))) float floatx4;  // MFMA C/D frag

#define D_MODEL 1024
#define SEQ 2048
#define NTOK 4096      // B*S
#define DK 64
#define NH 16
#define MAT 4194304    // NTOK*D_MODEL
#define WMAT 1048576   // D_MODEL*D_MODEL

static __device__ __forceinline__ unsigned short f2bf(float f) {
    unsigned int x = __float_as_uint(f);
    unsigned int r = x + 0x7fffu + ((x >> 16) & 1u);   // RNE
    return (unsigned short)(r >> 16);
}
static __device__ __forceinline__ float bf2f(unsigned short u) {
    return __uint_as_float(((unsigned int)u) << 16);
}
static __device__ __forceinline__ unsigned pk2(float x, float y) {
    __hip_bfloat162 h = __float22bfloat162_rn(make_float2(x, y));
    return *reinterpret_cast<unsigned*>(&h);
}
static __device__ __forceinline__ short8 cvt8(float4 f0, float4 f1) {
    union { unsigned u[4]; short8 s; } r;
    r.u[0] = pk2(f0.x, f0.y); r.u[1] = pk2(f0.z, f0.w);
    r.u[2] = pk2(f1.x, f1.y); r.u[3] = pk2(f1.z, f1.w);
    return r.s;
}
// token permutation within a 64-token tile: t=c*16+g*4+e -> g*16+c*4+e
static __device__ __forceinline__ int permtok(int t) {
    return ((t >> 2) & 3) * 16 + ((t >> 4) & 3) * 4 + (t & 3);
}

// ---------------------------------------------------------------------------
// fp32 -> bf16 conversion pass: xq,xk,xv (4M each) + wq,wk,wv,wo (1M each)
// ---------------------------------------------------------------------------
__global__ __launch_bounds__(256) void cvt7(
    const float* __restrict__ s0, const float* __restrict__ s1,
    const float* __restrict__ s2, const float* __restrict__ s3,
    const float* __restrict__ s4, const float* __restrict__ s5,
    const float* __restrict__ s6, unsigned short* __restrict__ dst) {
    const float* s; size_t doff; int n;
    switch (blockIdx.y) {
        case 0: s = s0; doff = 0;                          n = MAT;  break;
        case 1: s = s1; doff = (size_t)MAT;                n = MAT;  break;
        case 2: s = s2; doff = (size_t)2 * MAT;            n = MAT;  break;
        case 3: s = s3; doff = (size_t)3 * MAT;            n = WMAT; break;
        case 4: s = s4; doff = (size_t)3 * MAT + WMAT;     n = WMAT; break;
        case 5: s = s5; doff = (size_t)3 * MAT + 2 * WMAT; n = WMAT; break;
        default: s = s6; doff = (size_t)3 * MAT + 3 * WMAT; n = WMAT; break;
    }
    int idx = (blockIdx.x * 256 + threadIdx.x) * 8;
    if (idx >= n) return;
    float4 a = *(const float4*)(s + idx);
    float4 b = *(const float4*)(s + idx + 4);
    *(short8*)&dst[doff + idx] = cvt8(a, b);
}

// ---------------------------------------------------------------------------
// 128x128 NT GEMM, bf16 operands: out[m,n] = sum_k X[m,k]*W[n,k] + bias
// ROWBIAS: bias indexed by m (for transposed-output GEMMs). PERMN: permute
// output column within 64-token tiles (for V^T). OSTRIDE: out row stride.
// LDS: stride-64 rows + XOR swizzle -> conflict-free b128 reads.
// ---------------------------------------------------------------------------
template <bool F32OUT, bool ROWBIAS, bool PERMN, int OSTRIDE>
static __device__ __forceinline__ void gemm_bb(const unsigned short* __restrict__ X,
                                               const unsigned short* __restrict__ W,
                                               const float* __restrict__ bias,
                                               void* __restrict__ outp) {
    __shared__ __align__(16) unsigned short Asm[128 * 64];
    __shared__ __align__(16) unsigned short Bsm[128 * 64];

    const int tid = threadIdx.x;
    const int lane = tid & 63;
    const int wv = tid >> 6;
    const int g = lane >> 4;
    const int lm = lane & 15;
    const int wr = wv >> 1;
    const int wc = wv & 1;
    const int m0 = blockIdx.y * 128;
    const int n0 = blockIdx.x * 128;
    const int rs = (lm & 7) << 3;          // read-side swizzle

    floatx4 acc[4][4];
#pragma unroll
    for (int mi = 0; mi < 4; ++mi)
#pragma unroll
        for (int ni = 0; ni < 4; ++ni)
            acc[mi][ni] = (floatx4){0.f, 0.f, 0.f, 0.f};

    for (int k0 = 0; k0 < 1024; k0 += 64) {
#pragma unroll
        for (int i = 0; i < 4; ++i) {
            int idx = tid + i * 256;
            int row = idx >> 3;
            int col = (idx & 7) << 3;
            int sc = col ^ ((row & 7) << 3);
            *(uint4*)&Asm[row * 64 + sc] =
                *(const uint4*)&X[(size_t)(m0 + row) * 1024 + k0 + col];
            *(uint4*)&Bsm[row * 64 + sc] =
                *(const uint4*)&W[(size_t)(n0 + row) * 1024 + k0 + col];
        }
        __syncthreads();
#pragma unroll
        for (int ks = 0; ks < 64; ks += 32) {
            short8 af[4], bfr[4];
#pragma unroll
            for (int mi = 0; mi < 4; ++mi)
                af[mi] = *(const short8*)&Asm[(wr * 64 + mi * 16 + lm) * 64 +
                                              ((ks + g * 8) ^ rs)];
#pragma unroll
            for (int ni = 0; ni < 4; ++ni)
                bfr[ni] = *(const short8*)&Bsm[(wc * 64 + ni * 16 + lm) * 64 +
                                               ((ks + g * 8) ^ rs)];
#pragma unroll
            for (int mi = 0; mi < 4; ++mi)
#pragma unroll
                for (int ni = 0; ni < 4; ++ni)
                    acc[mi][ni] = __builtin_amdgcn_mfma_f32_16x16x32_bf16(
                        af[mi], bfr[ni], acc[mi][ni], 0, 0, 0);
        }
        __syncthreads();
    }

    float cb[4];
#pragma unroll
    for (int ni = 0; ni < 4; ++ni)
        cb[ni] = ROWBIAS ? 0.f : bias[n0 + wc * 64 + ni * 16 + lm];
#pragma unroll
    for (int mi = 0; mi < 4; ++mi)
#pragma unroll
        for (int r = 0; r < 4; ++r) {
            int rowg = m0 + wr * 64 + mi * 16 + g * 4 + r;
            float rb = ROWBIAS ? bias[rowg] : 0.f;
#pragma unroll
            for (int ni = 0; ni < 4; ++ni) {
                int colg = n0 + wc * 64 + ni * 16 + lm;
                if (PERMN) colg = (colg & ~63) | permtok(colg & 63);
                float val = acc[mi][ni][r] + (ROWBIAS ? rb : cb[ni]);
                if (F32OUT)
                    ((float*)outp)[(size_t)rowg * OSTRIDE + colg] = val;
                else
                    ((unsigned short*)outp)[(size_t)rowg * OSTRIDE + colg] = f2bf(val);
            }
        }
}

__global__ __launch_bounds__(256) void qkv_gemm_b(
    const unsigned short* __restrict__ Xb, const unsigned short* __restrict__ Wb,
    const float* __restrict__ bq, const float* __restrict__ bk,
    unsigned short* __restrict__ QK) {
    const int z = blockIdx.z;                    // 0 = Q, 1 = K
    const float* bias = (z == 0) ? bq : bk;
    gemm_bb<false, false, false, 1024>(Xb + (size_t)z * MAT, Wb + (size_t)z * WMAT,
                                       bias, QK + (size_t)z * MAT);
}

// V^T projection: out[m=feature][n=token(permuted)] = sum_k Wv[m,k]*Xv[n,k] + bv[m]
__global__ __launch_bounds__(256) void vt_gemm_b(
    const unsigned short* __restrict__ Wv, const unsigned short* __restrict__ Xv,
    const float* __restrict__ bv, unsigned short* __restrict__ VT) {
    gemm_bb<false, true, true, 4096>(Wv, Xv, bv, VT);
}

__global__ __launch_bounds__(256) void out_gemm_b(
    const unsigned short* __restrict__ ctx, const unsigned short* __restrict__ Wo,
    const float* __restrict__ bo, float* __restrict__ out) {
    gemm_bb<true, false, false, 1024>(ctx, Wo, bo, out);
}

// ---------------- fallback path (fp32 staging), used if ws too small --------
template <bool ROWBIAS, bool PERMN, int OSTRIDE>
static __device__ __forceinline__ void gemm128_f(const float* __restrict__ X,
                                                 const float* __restrict__ W,
                                                 const float* __restrict__ bias,
                                                 unsigned short* __restrict__ out) {
    __shared__ __align__(16) unsigned short Asm[128 * 72];
    __shared__ __align__(16) unsigned short Bsm[128 * 72];
    const int tid = threadIdx.x;
    const int lane = tid & 63;
    const int wv = tid >> 6;
    const int g = lane >> 4;
    const int lm = lane & 15;
    const int wr = wv >> 1;
    const int wc = wv & 1;
    const int m0 = blockIdx.y * 128;
    const int n0 = blockIdx.x * 128;
    floatx4 acc[4][4];
#pragma unroll
    for (int mi = 0; mi < 4; ++mi)
#pragma unroll
        for (int ni = 0; ni < 4; ++ni)
            acc[mi][ni] = (floatx4){0.f, 0.f, 0.f, 0.f};
    for (int k0 = 0; k0 < 1024; k0 += 64) {
#pragma unroll
        for (int i = 0; i < 4; ++i) {
            int idx = tid + i * 256;
            int row = idx >> 3;
            int col = (idx & 7) << 3;
            const float* sa = &X[(size_t)(m0 + row) * 1024 + k0 + col];
            *(short8*)&Asm[row * 72 + col] = cvt8(*(const float4*)sa, *(const float4*)(sa + 4));
            const float* sb = &W[(size_t)(n0 + row) * 1024 + k0 + col];
            *(short8*)&Bsm[row * 72 + col] = cvt8(*(const float4*)sb, *(const float4*)(sb + 4));
        }
        __syncthreads();
#pragma unroll
        for (int ks = 0; ks < 64; ks += 32) {
            short8 af[4], bfr[4];
#pragma unroll
            for (int mi = 0; mi < 4; ++mi)
                af[mi] = *(const short8*)&Asm[(wr * 64 + mi * 16 + lm) * 72 + ks + g * 8];
#pragma unroll
            for (int ni = 0; ni < 4; ++ni)
                bfr[ni] = *(const short8*)&Bsm[(wc * 64 + ni * 16 + lm) * 72 + ks + g * 8];
#pragma unroll
            for (int mi = 0; mi < 4; ++mi)
#pragma unroll
                for (int ni = 0; ni < 4; ++ni)
                    acc[mi][ni] = __builtin_amdgcn_mfma_f32_16x16x32_bf16(
                        af[mi], bfr[ni], acc[mi][ni], 0, 0, 0);
        }
        __syncthreads();
    }
    float cb[4];
#pragma unroll
    for (int ni = 0; ni < 4; ++ni)
        cb[ni] = ROWBIAS ? 0.f : bias[n0 + wc * 64 + ni * 16 + lm];
#pragma unroll
    for (int mi = 0; mi < 4; ++mi)
#pragma unroll
        for (int r = 0; r < 4; ++r) {
            int rowg = m0 + wr * 64 + mi * 16 + g * 4 + r;
            float rb = ROWBIAS ? bias[rowg] : 0.f;
#pragma unroll
            for (int ni = 0; ni < 4; ++ni) {
                int colg = n0 + wc * 64 + ni * 16 + lm;
                if (PERMN) colg = (colg & ~63) | permtok(colg & 63);
                out[(size_t)rowg * OSTRIDE + colg] =
                    f2bf(acc[mi][ni][r] + (ROWBIAS ? rb : cb[ni]));
            }
        }
}

__global__ __launch_bounds__(256) void qkv_gemm_f(
    const float* __restrict__ xq, const float* __restrict__ xk,
    const float* __restrict__ wq, const float* __restrict__ wk,
    const float* __restrict__ bq, const float* __restrict__ bk,
    unsigned short* __restrict__ q, unsigned short* __restrict__ k) {
    if (blockIdx.z == 0) gemm128_f<false, false, 1024>(xq, wq, bq, q);
    else                 gemm128_f<false, false, 1024>(xk, wk, bk, k);
}

__global__ __launch_bounds__(256) void vt_gemm_f(
    const float* __restrict__ wv, const float* __restrict__ xv,
    const float* __restrict__ bv, unsigned short* __restrict__ VT) {
    gemm128_f<true, true, 4096>(wv, xv, bv, VT);
}

__global__ __launch_bounds__(256) void out_gemm_f(
    const float* __restrict__ wo, const float* __restrict__ bo,
    const unsigned short* __restrict__ ctx, float* __restrict__ out) {
    __shared__ __align__(16) unsigned short Asm[128 * 72];
    __shared__ __align__(16) unsigned short Bsm[128 * 72];
    const int tid = threadIdx.x;
    const int lane = tid & 63;
    const int wv = tid >> 6;
    const int g = lane >> 4;
    const int lm = lane & 15;
    const int wr = wv >> 1;
    const int wc = wv & 1;
    const int m0 = blockIdx.y * 128;
    const int n0 = blockIdx.x * 128;
    floatx4 acc[4][4];
#pragma unroll
    for (int mi = 0; mi < 4; ++mi)
#pragma unroll
        for (int ni = 0; ni < 4; ++ni)
            acc[mi][ni] = (floatx4){0.f, 0.f, 0.f, 0.f};
    for (int k0 = 0; k0 < 1024; k0 += 64) {
#pragma unroll
        for (int i = 0; i < 4; ++i) {
            int idx = tid + i * 256;
            int row = idx >> 3;
            int col = (idx & 7) << 3;
            *(uint4*)&Asm[row * 72 + col] =
                *(const uint4*)&ctx[(size_t)(m0 + row) * 1024 + k0 + col];
            const float* sb = &wo[(size_t)(n0 + row) * 1024 + k0 + col];
            *(short8*)&Bsm[row * 72 + col] = cvt8(*(const float4*)sb, *(const float4*)(sb + 4));
        }
        __syncthreads();
#pragma unroll
        for (int ks = 0; ks < 64; ks += 32) {
            short8 af[4], bfr[4];
#pragma unroll
            for (int mi = 0; mi < 4; ++mi)
                af[mi] = *(const short8*)&Asm[(wr * 64 + mi * 16 + lm) * 72 + ks + g * 8];
#pragma unroll
            for (int ni = 0; ni < 4; ++ni)
                bfr[ni] = *(const short8*)&Bsm[(wc * 64 + ni * 16 + lm) * 72 + ks + g * 8];
#pragma unroll
            for (int mi = 0; mi < 4; ++mi)
#pragma unroll
                for (int ni = 0; ni < 4; ++ni)
                    acc[mi][ni] = __builtin_amdgcn_mfma_f32_16x16x32_bf16(
                        af[mi], bfr[ni], acc[mi][ni], 0, 0, 0);
        }
        __syncthreads();
    }
    float bb[4];
#pragma unroll
    for (int ni = 0; ni < 4; ++ni)
        bb[ni] = bo[n0 + wc * 64 + ni * 16 + lm];
#pragma unroll
    for (int mi = 0; mi < 4; ++mi)
#pragma unroll
        for (int ni = 0; ni < 4; ++ni)
#pragma unroll
            for (int r = 0; r < 4; ++r) {
                int rowg = m0 + wr * 64 + mi * 16 + g * 4 + r;
                int colg = n0 + wc * 64 + ni * 16 + lm;
                out[(size_t)rowg * 1024 + colg] = acc[mi][ni][r] + bb[ni];
            }
}

// ---------------------------------------------------------------------------
// Flash attention v6: QBLK=32 q-rows per wave (2 q-subtiles share K/Vt frags),
// stride-64 + XOR-swizzled LDS (conflict-free b128 reads), Vt token-permuted
// so PV B-operand is one b128 read. Grid bh-major for per-XCD L2 K/V reuse.
//   S^T = mfma(K_frag, Q_frag): C rows = keys kb*16+g*4+r, cols = q lm.
//   PV slot map (slot g*8+j <-> key c*16+g*4+(j&3), c=2cp+(j>>2)) realized
//   directly by the permuted Vt layout: LDS col g*16+cp*8+j holds that key.
// ---------------------------------------------------------------------------
__global__ __launch_bounds__(256) void attn_kernel(
    const unsigned short* __restrict__ Q, const unsigned short* __restrict__ K,
    const unsigned short* __restrict__ VT, unsigned short* __restrict__ CTX) {
    __shared__ __align__(16) unsigned short Ksm[64 * 64];
    __shared__ __align__(16) unsigned short Vt[64 * 64];

    const int tid = threadIdx.x;
    const int lane = tid & 63;
    const int w = tid >> 6;
    const int g = lane >> 4;
    const int lm = lane & 15;
    const int bh = blockIdx.x;       // bh-major: same-head blocks share an XCD's L2
    const int qt = blockIdx.y;
    const int b = bh >> 4;
    const int h = bh & 15;

    const size_t base = (size_t)b * SEQ * D_MODEL + (size_t)h * DK;
    // VT: [1024 features][4096 tokens, permuted within 64-tiles]
    const size_t vtbase = (size_t)(h * 64) * NTOK + (size_t)b * SEQ;

    // staging coords (shared by K and Vt tiles)
    const int srow0 = tid >> 3;            // 0..31   (+32 on second iter)
    const int scol = (tid & 7) << 3;       // 0,8,...,56
    const int swz = scol ^ ((srow0 & 7) << 3);   // (srow0+32)&7 == srow0&7
    const int rs = (lm & 7) << 3;                // read-side swizzle

    // Q fragments (B-operand for S^T), prescaled by 1/8; 2 q-subtiles
    short8 qf[2][2];
#pragma unroll
    for (int qs = 0; qs < 2; ++qs) {
        const int qrow = qt * 128 + w * 32 + qs * 16 + lm;
#pragma unroll
        for (int t = 0; t < 2; ++t) {
            short8 raw = *(const short8*)&Q[base + (size_t)qrow * D_MODEL + t * 32 + g * 8];
            union { unsigned u[4]; short8 s; } r;
#pragma unroll
            for (int j = 0; j < 4; ++j) {
                float lo = bf2f((unsigned short)raw[2 * j]) * 0.125f;
                float hi = bf2f((unsigned short)raw[2 * j + 1]) * 0.125f;
                r.u[j] = pk2(lo, hi);
            }
            qf[qs][t] = r.s;
        }
    }

    float lsum[2] = {0.f, 0.f};
    floatx4 Oacc[2][4];
#pragma unroll
    for (int qs = 0; qs < 2; ++qs)
#pragma unroll
        for (int nb = 0; nb < 4; ++nb) Oacc[qs][nb] = (floatx4){0.f, 0.f, 0.f, 0.f};

    for (int kt = 0; kt < SEQ / 64; ++kt) {
        const int krow0 = kt * 64;
        // ---- stage K and Vt tiles: coalesced uint4 load -> swizzled LDS write
#pragma unroll
        for (int i = 0; i < 2; ++i) {
            int row = srow0 + i * 32;
            *(uint4*)&Ksm[row * 64 + swz] =
                *(const uint4*)&K[base + (size_t)(krow0 + row) * D_MODEL + scol];
            *(uint4*)&Vt[row * 64 + swz] =
                *(const uint4*)&VT[vtbase + (size_t)row * NTOK + krow0 + scol];
        }
        __syncthreads();

        // ---- S^T = K Q^T / 8 : per kb, rows = keys kb*16+g*4+r, col q=lm ----
        // K fragments read ONCE, used by both q-subtiles.
        float p[2][4][4];
#pragma unroll
        for (int kb = 0; kb < 4; ++kb) {
            short8 ak0 = *(const short8*)&Ksm[(kb * 16 + lm) * 64 + ((0 + g * 8) ^ rs)];
            short8 ak1 = *(const short8*)&Ksm[(kb * 16 + lm) * 64 + ((32 + g * 8) ^ rs)];
#pragma unroll
            for (int qs = 0; qs < 2; ++qs) {
                floatx4 a = (floatx4){0.f, 0.f, 0.f, 0.f};
                a = __builtin_amdgcn_mfma_f32_16x16x32_bf16(ak0, qf[qs][0], a, 0, 0, 0);
                a = __builtin_amdgcn_mfma_f32_16x16x32_bf16(ak1, qf[qs][1], a, 0, 0, 0);
#pragma unroll
                for (int r = 0; r < 4; ++r) p[qs][kb][r] = __expf(a[r]);
                lsum[qs] += (p[qs][kb][0] + p[qs][kb][1]) + (p[qs][kb][2] + p[qs][kb][3]);
            }
        }

        // ---- O += P V : Vt fragments read ONCE (b128), used by both subtiles
#pragma unroll
        for (int cp = 0; cp < 2; ++cp) {
            const int c0 = 2 * cp, c1 = 2 * cp + 1;
            union { unsigned u[4]; short8 s; } ap[2];
#pragma unroll
            for (int qs = 0; qs < 2; ++qs) {
                ap[qs].u[0] = pk2(p[qs][c0][0], p[qs][c0][1]);
                ap[qs].u[1] = pk2(p[qs][c0][2], p[qs][c0][3]);
                ap[qs].u[2] = pk2(p[qs][c1][0], p[qs][c1][1]);
                ap[qs].u[3] = pk2(p[qs][c1][2], p[qs][c1][3]);
            }
#pragma unroll
            for (int nb = 0; nb < 4; ++nb) {
                const int d = nb * 16 + lm;
                short8 bv = *(const short8*)&Vt[d * 64 + ((g * 16 + cp * 8) ^ rs)];
                Oacc[0][nb] = __builtin_amdgcn_mfma_f32_16x16x32_bf16(
                    ap[0].s, bv, Oacc[0][nb], 0, 0, 0);
                Oacc[1][nb] = __builtin_amdgcn_mfma_f32_16x16x32_bf16(
                    ap[1].s, bv, Oacc[1][nb], 0, 0, 0);
            }
        }
        __syncthreads();
    }

    // ---- softmax denominator: reduce over g, redistribute to rows ----
#pragma unroll
    for (int qs = 0; qs < 2; ++qs) {
        float l = lsum[qs];
        l += __shfl_xor(l, 16, 64);
        l += __shfl_xor(l, 32, 64);   // all lanes: full l for q = w*32+qs*16+lm
        float lr[4];
#pragma unroll
        for (int r = 0; r < 4; ++r)
            lr[r] = __shfl(l, g * 4 + r, 64);   // l for q-row = ...+g*4+r
#pragma unroll
        for (int nb = 0; nb < 4; ++nb) {
#pragma unroll
            for (int r = 0; r < 4; ++r) {
                float val = Oacc[qs][nb][r] / lr[r];
                int srow = qt * 128 + w * 32 + qs * 16 + g * 4 + r;
                CTX[base + (size_t)srow * D_MODEL + nb * 16 + lm] = f2bf(val);
            }
        }
    }
}

extern "C" void kernel_launch(void* const* d_in, const int* in_sizes, int n_in,
                              void* d_out, int out_size, void* d_ws, size_t ws_size,
                              hipStream_t stream) {
    const float* xq = (const float*)d_in[0];
    const float* xk = (const float*)d_in[1];
    const float* xv = (const float*)d_in[2];
    const float* wq = (const float*)d_in[3];
    const float* bq = (const float*)d_in[4];
    const float* wk = (const float*)d_in[5];
    const float* bk = (const float*)d_in[6];
    const float* wv = (const float*)d_in[7];
    const float* bv = (const float*)d_in[8];
    const float* wo = (const float*)d_in[9];
    const float* bo = (const float*)d_in[10];
    float* out = (float*)d_out;

    unsigned short* ws = (unsigned short*)d_ws;

    if (ws_size >= (size_t)68 * 1024 * 1024) {
        // bf16 path: Xb[3*MAT] | Wb[4*WMAT] | Q | K | VT | C
        unsigned short* Xb = ws;
        unsigned short* Wb = ws + (size_t)3 * MAT;
        unsigned short* Qw = Wb + (size_t)4 * WMAT;
        unsigned short* Kw = Qw + (size_t)MAT;
        unsigned short* VTw = Kw + (size_t)MAT;
        unsigned short* Cw = VTw + (size_t)MAT;

        cvt7<<<dim3(2048, 7), 256, 0, stream>>>(xq, xk, xv, wq, wk, wv, wo, ws);
        qkv_gemm_b<<<dim3(8, 32, 2), 256, 0, stream>>>(Xb, Wb, bq, bk, Qw);
        vt_gemm_b<<<dim3(32, 8), 256, 0, stream>>>(
            Wb + (size_t)2 * WMAT, Xb + (size_t)2 * MAT, bv, VTw);
        attn_kernel<<<dim3(2 * NH, SEQ / 128), 256, 0, stream>>>(Qw, Kw, VTw, Cw);
        out_gemm_b<<<dim3(8, 32), 256, 0, stream>>>(Cw, Wb + (size_t)3 * WMAT, bo, out);
    } else {
        unsigned short* Qw = ws;
        unsigned short* Kw = ws + (size_t)MAT;
        unsigned short* VTw = ws + (size_t)2 * MAT;
        unsigned short* Cw = ws + (size_t)3 * MAT;
        qkv_gemm_f<<<dim3(8, 32, 2), 256, 0, stream>>>(xq, xk, wq, wk, bq, bk, Qw, Kw);
        vt_gemm_f<<<dim3(32, 8), 256, 0, stream>>>(wv, xv, bv, VTw);
        attn_kernel<<<dim3(2 * NH, SEQ / 128), 256, 0, stream>>>(Qw, Kw, VTw, Cw);
        out_gemm_f<<<dim3(8, 32), 256, 0, stream>>>(wo, bo, Cw, out);
    }
}

// Round 2
// 234.958 us; speedup vs baseline: 1.1361x; 1.0470x over previous
//
#include <hip/hip_runtime.h>
#include <hip/hip_bf16.h>

// MultiheadAttention: B=2, S=2048, D=1024, H=16, dk=64.
// Inputs fp32, output fp32. Internals bf16 MFMA.
// V is produced TRANSPOSED ([feature][token]) by its projection GEMM, with
// tokens PERMUTED within each 64-token tile (t=c*16+g*4+e -> g*16+c*4+e) so
// the attention PV B-operand is a single contiguous b128 LDS read.
// All LDS tiles: stride-64 rows, XOR swizzle col ^= ((row&7)<<3) (16B granule).
// Staging: global_load_lds width=16 with PRE-SWIZZLED GLOBAL SOURCE (linear
// LDS dest + inverse-swizzled source + swizzled read; XOR is an involution so
// source-swz == read-swz). Double-buffered LDS, ONE __syncthreads per tile:
// prefetch for tile t+1 issued after the barrier, lands during compute of t,
// so the barrier's implicit vmcnt(0) drain is near-free.

typedef __attribute__((ext_vector_type(8))) short short8;   // 8 bf16 = 4 VGPR (MFMA A/B frag)
typedef __attribute__((ext_vector_type(4))) float floatx4;  // MFMA C/D frag

#define D_MODEL 1024
#define SEQ 2048
#define NTOK 4096      // B*S
#define DK 64
#define NH 16
#define MAT 4194304    // NTOK*D_MODEL
#define WMAT 1048576   // D_MODEL*D_MODEL

static __device__ __forceinline__ unsigned short f2bf(float f) {
    unsigned int x = __float_as_uint(f);
    unsigned int r = x + 0x7fffu + ((x >> 16) & 1u);   // RNE
    return (unsigned short)(r >> 16);
}
static __device__ __forceinline__ float bf2f(unsigned short u) {
    return __uint_as_float(((unsigned int)u) << 16);
}
static __device__ __forceinline__ unsigned pk2(float x, float y) {
    __hip_bfloat162 h = __float22bfloat162_rn(make_float2(x, y));
    return *reinterpret_cast<unsigned*>(&h);
}
static __device__ __forceinline__ short8 cvt8(float4 f0, float4 f1) {
    union { unsigned u[4]; short8 s; } r;
    r.u[0] = pk2(f0.x, f0.y); r.u[1] = pk2(f0.z, f0.w);
    r.u[2] = pk2(f1.x, f1.y); r.u[3] = pk2(f1.z, f1.w);
    return r.s;
}
// token permutation within a 64-token tile: t=c*16+g*4+e -> g*16+c*4+e
static __device__ __forceinline__ int permtok(int t) {
    return ((t >> 2) & 3) * 16 + ((t >> 4) & 3) * 4 + (t & 3);
}
// async global->LDS, 16B per lane; LDS dest = wave-uniform base + lane*16
static __device__ __forceinline__ void glds16(const unsigned short* g, unsigned short* l) {
    __builtin_amdgcn_global_load_lds(
        (const __attribute__((address_space(1))) void*)g,
        (__attribute__((address_space(3))) void*)l, 16, 0, 0);
}

// ---------------------------------------------------------------------------
// fp32 -> bf16 conversion pass: xq,xk,xv (4M each) + wq,wk,wv,wo (1M each)
// ---------------------------------------------------------------------------
__global__ __launch_bounds__(256) void cvt7(
    const float* __restrict__ s0, const float* __restrict__ s1,
    const float* __restrict__ s2, const float* __restrict__ s3,
    const float* __restrict__ s4, const float* __restrict__ s5,
    const float* __restrict__ s6, unsigned short* __restrict__ dst) {
    const float* s; size_t doff; int n;
    switch (blockIdx.y) {
        case 0: s = s0; doff = 0;                          n = MAT;  break;
        case 1: s = s1; doff = (size_t)MAT;                n = MAT;  break;
        case 2: s = s2; doff = (size_t)2 * MAT;            n = MAT;  break;
        case 3: s = s3; doff = (size_t)3 * MAT;            n = WMAT; break;
        case 4: s = s4; doff = (size_t)3 * MAT + WMAT;     n = WMAT; break;
        case 5: s = s5; doff = (size_t)3 * MAT + 2 * WMAT; n = WMAT; break;
        default: s = s6; doff = (size_t)3 * MAT + 3 * WMAT; n = WMAT; break;
    }
    int idx = (blockIdx.x * 256 + threadIdx.x) * 8;
    if (idx >= n) return;
    float4 a = *(const float4*)(s + idx);
    float4 b = *(const float4*)(s + idx + 4);
    *(short8*)&dst[doff + idx] = cvt8(a, b);
}

// ---------------------------------------------------------------------------
// BMx128 NT GEMM, bf16 operands: out[m,n] = sum_k X[m,k]*W[n,k] + bias
// Double-buffered LDS, global_load_lds staging (pre-swizzled source), one
// __syncthreads per k-step with prefetch issued post-barrier.
// ---------------------------------------------------------------------------
template <bool F32OUT, bool ROWBIAS, bool PERMN, int OSTRIDE, int BM>
static __device__ __forceinline__ void gemm_bb(const unsigned short* __restrict__ X,
                                               const unsigned short* __restrict__ W,
                                               const float* __restrict__ bias,
                                               void* __restrict__ outp) {
    __shared__ __align__(16) unsigned short Asm[2][BM * 64];
    __shared__ __align__(16) unsigned short Bsm[2][128 * 64];
    constexpr int MF = BM / 32;          // m-fragments per wave
    constexpr int HALF = BM / 2;

    const int tid = threadIdx.x;
    const int lane = tid & 63;
    const int wv = tid >> 6;
    const int g = lane >> 4;
    const int lm = lane & 15;
    const int wr = wv >> 1;
    const int wc = wv & 1;
    const int m0 = blockIdx.y * BM;
    const int n0 = blockIdx.x * 128;
    const int rs = (lm & 7) << 3;          // read-side swizzle
    const int lr = lane >> 3;              // 0..7 : row within a glds group
    const int lc = lane & 7;               // 16B slot within row

    auto issue = [&](int k0, int p) {
#pragma unroll
        for (int i = 0; i < BM / 32; ++i) {
            const int r0 = wv * (BM / 4) + i * 8;
            const int row = r0 + lr;
            const int gcol = (lc ^ (row & 7)) << 3;
            glds16(&X[(size_t)(m0 + row) * 1024 + k0 + gcol], &Asm[p][r0 * 64]);
        }
#pragma unroll
        for (int i = 0; i < 4; ++i) {
            const int r0 = wv * 32 + i * 8;
            const int row = r0 + lr;
            const int gcol = (lc ^ (row & 7)) << 3;
            glds16(&W[(size_t)(n0 + row) * 1024 + k0 + gcol], &Bsm[p][r0 * 64]);
        }
    };

    floatx4 acc[MF][4];
#pragma unroll
    for (int mi = 0; mi < MF; ++mi)
#pragma unroll
        for (int ni = 0; ni < 4; ++ni)
            acc[mi][ni] = (floatx4){0.f, 0.f, 0.f, 0.f};

    issue(0, 0);
    for (int k0 = 0, it = 0; k0 < 1024; k0 += 64, ++it) {
        const int p = it & 1;
        __syncthreads();                         // vmcnt drain: tile it in LDS, all waves
        if (k0 + 64 < 1024) issue(k0 + 64, p ^ 1);   // prefetch lands during compute
#pragma unroll
        for (int ks = 0; ks < 64; ks += 32) {
            short8 af[MF], bfr[4];
#pragma unroll
            for (int mi = 0; mi < MF; ++mi)
                af[mi] = *(const short8*)&Asm[p][(wr * HALF + mi * 16 + lm) * 64 +
                                                ((ks + g * 8) ^ rs)];
#pragma unroll
            for (int ni = 0; ni < 4; ++ni)
                bfr[ni] = *(const short8*)&Bsm[p][(wc * 64 + ni * 16 + lm) * 64 +
                                                 ((ks + g * 8) ^ rs)];
#pragma unroll
            for (int mi = 0; mi < MF; ++mi)
#pragma unroll
                for (int ni = 0; ni < 4; ++ni)
                    acc[mi][ni] = __builtin_amdgcn_mfma_f32_16x16x32_bf16(
                        af[mi], bfr[ni], acc[mi][ni], 0, 0, 0);
        }
    }

    float cb[4];
#pragma unroll
    for (int ni = 0; ni < 4; ++ni)
        cb[ni] = ROWBIAS ? 0.f : bias[n0 + wc * 64 + ni * 16 + lm];
#pragma unroll
    for (int mi = 0; mi < MF; ++mi)
#pragma unroll
        for (int r = 0; r < 4; ++r) {
            int rowg = m0 + wr * HALF + mi * 16 + g * 4 + r;
            float rb = ROWBIAS ? bias[rowg] : 0.f;
#pragma unroll
            for (int ni = 0; ni < 4; ++ni) {
                int colg = n0 + wc * 64 + ni * 16 + lm;
                if (PERMN) colg = (colg & ~63) | permtok(colg & 63);
                float val = acc[mi][ni][r] + (ROWBIAS ? rb : cb[ni]);
                if (F32OUT)
                    ((float*)outp)[(size_t)rowg * OSTRIDE + colg] = val;
                else
                    ((unsigned short*)outp)[(size_t)rowg * OSTRIDE + colg] = f2bf(val);
            }
        }
}

__global__ __launch_bounds__(256) void qkv_gemm_b(
    const unsigned short* __restrict__ Xb, const unsigned short* __restrict__ Wb,
    const float* __restrict__ bq, const float* __restrict__ bk,
    unsigned short* __restrict__ QK) {
    const int z = blockIdx.z;                    // 0 = Q, 1 = K
    const float* bias = (z == 0) ? bq : bk;
    gemm_bb<false, false, false, 1024, 128>(Xb + (size_t)z * MAT, Wb + (size_t)z * WMAT,
                                            bias, QK + (size_t)z * MAT);
}

// V^T projection: out[m=feature][n=token(permuted)] = sum_k Wv[m,k]*Xv[n,k] + bv[m]
__global__ __launch_bounds__(256) void vt_gemm_b(
    const unsigned short* __restrict__ Wv, const unsigned short* __restrict__ Xv,
    const float* __restrict__ bv, unsigned short* __restrict__ VT) {
    gemm_bb<false, true, true, 4096, 64>(Wv, Xv, bv, VT);
}

__global__ __launch_bounds__(256) void out_gemm_b(
    const unsigned short* __restrict__ ctx, const unsigned short* __restrict__ Wo,
    const float* __restrict__ bo, float* __restrict__ out) {
    gemm_bb<true, false, false, 1024, 64>(ctx, Wo, bo, out);
}

// ---------------- fallback path (fp32 staging), used if ws too small --------
template <bool ROWBIAS, bool PERMN, int OSTRIDE>
static __device__ __forceinline__ void gemm128_f(const float* __restrict__ X,
                                                 const float* __restrict__ W,
                                                 const float* __restrict__ bias,
                                                 unsigned short* __restrict__ out) {
    __shared__ __align__(16) unsigned short Asm[128 * 72];
    __shared__ __align__(16) unsigned short Bsm[128 * 72];
    const int tid = threadIdx.x;
    const int lane = tid & 63;
    const int wv = tid >> 6;
    const int g = lane >> 4;
    const int lm = lane & 15;
    const int wr = wv >> 1;
    const int wc = wv & 1;
    const int m0 = blockIdx.y * 128;
    const int n0 = blockIdx.x * 128;
    floatx4 acc[4][4];
#pragma unroll
    for (int mi = 0; mi < 4; ++mi)
#pragma unroll
        for (int ni = 0; ni < 4; ++ni)
            acc[mi][ni] = (floatx4){0.f, 0.f, 0.f, 0.f};
    for (int k0 = 0; k0 < 1024; k0 += 64) {
#pragma unroll
        for (int i = 0; i < 4; ++i) {
            int idx = tid + i * 256;
            int row = idx >> 3;
            int col = (idx & 7) << 3;
            const float* sa = &X[(size_t)(m0 + row) * 1024 + k0 + col];
            *(short8*)&Asm[row * 72 + col] = cvt8(*(const float4*)sa, *(const float4*)(sa + 4));
            const float* sb = &W[(size_t)(n0 + row) * 1024 + k0 + col];
            *(short8*)&Bsm[row * 72 + col] = cvt8(*(const float4*)sb, *(const float4*)(sb + 4));
        }
        __syncthreads();
#pragma unroll
        for (int ks = 0; ks < 64; ks += 32) {
            short8 af[4], bfr[4];
#pragma unroll
            for (int mi = 0; mi < 4; ++mi)
                af[mi] = *(const short8*)&Asm[(wr * 64 + mi * 16 + lm) * 72 + ks + g * 8];
#pragma unroll
            for (int ni = 0; ni < 4; ++ni)
                bfr[ni] = *(const short8*)&Bsm[(wc * 64 + ni * 16 + lm) * 72 + ks + g * 8];
#pragma unroll
            for (int mi = 0; mi < 4; ++mi)
#pragma unroll
                for (int ni = 0; ni < 4; ++ni)
                    acc[mi][ni] = __builtin_amdgcn_mfma_f32_16x16x32_bf16(
                        af[mi], bfr[ni], acc[mi][ni], 0, 0, 0);
        }
        __syncthreads();
    }
    float cb[4];
#pragma unroll
    for (int ni = 0; ni < 4; ++ni)
        cb[ni] = ROWBIAS ? 0.f : bias[n0 + wc * 64 + ni * 16 + lm];
#pragma unroll
    for (int mi = 0; mi < 4; ++mi)
#pragma unroll
        for (int r = 0; r < 4; ++r) {
            int rowg = m0 + wr * 64 + mi * 16 + g * 4 + r;
            float rb = ROWBIAS ? bias[rowg] : 0.f;
#pragma unroll
            for (int ni = 0; ni < 4; ++ni) {
                int colg = n0 + wc * 64 + ni * 16 + lm;
                if (PERMN) colg = (colg & ~63) | permtok(colg & 63);
                out[(size_t)rowg * OSTRIDE + colg] =
                    f2bf(acc[mi][ni][r] + (ROWBIAS ? rb : cb[ni]));
            }
        }
}

__global__ __launch_bounds__(256) void qkv_gemm_f(
    const float* __restrict__ xq, const float* __restrict__ xk,
    const float* __restrict__ wq, const float* __restrict__ wk,
    const float* __restrict__ bq, const float* __restrict__ bk,
    unsigned short* __restrict__ q, unsigned short* __restrict__ k) {
    if (blockIdx.z == 0) gemm128_f<false, false, 1024>(xq, wq, bq, q);
    else                 gemm128_f<false, false, 1024>(xk, wk, bk, k);
}

__global__ __launch_bounds__(256) void vt_gemm_f(
    const float* __restrict__ wv, const float* __restrict__ xv,
    const float* __restrict__ bv, unsigned short* __restrict__ VT) {
    gemm128_f<true, true, 4096>(wv, xv, bv, VT);
}

__global__ __launch_bounds__(256) void out_gemm_f(
    const float* __restrict__ wo, const float* __restrict__ bo,
    const unsigned short* __restrict__ ctx, float* __restrict__ out) {
    __shared__ __align__(16) unsigned short Asm[128 * 72];
    __shared__ __align__(16) unsigned short Bsm[128 * 72];
    const int tid = threadIdx.x;
    const int lane = tid & 63;
    const int wv = tid >> 6;
    const int g = lane >> 4;
    const int lm = lane & 15;
    const int wr = wv >> 1;
    const int wc = wv & 1;
    const int m0 = blockIdx.y * 128;
    const int n0 = blockIdx.x * 128;
    floatx4 acc[4][4];
#pragma unroll
    for (int mi = 0; mi < 4; ++mi)
#pragma unroll
        for (int ni = 0; ni < 4; ++ni)
            acc[mi][ni] = (floatx4){0.f, 0.f, 0.f, 0.f};
    for (int k0 = 0; k0 < 1024; k0 += 64) {
#pragma unroll
        for (int i = 0; i < 4; ++i) {
            int idx = tid + i * 256;
            int row = idx >> 3;
            int col = (idx & 7) << 3;
            *(uint4*)&Asm[row * 72 + col] =
                *(const uint4*)&ctx[(size_t)(m0 + row) * 1024 + k0 + col];
            const float* sb = &wo[(size_t)(n0 + row) * 1024 + k0 + col];
            *(short8*)&Bsm[row * 72 + col] = cvt8(*(const float4*)sb, *(const float4*)(sb + 4));
        }
        __syncthreads();
#pragma unroll
        for (int ks = 0; ks < 64; ks += 32) {
            short8 af[4], bfr[4];
#pragma unroll
            for (int mi = 0; mi < 4; ++mi)
                af[mi] = *(const short8*)&Asm[(wr * 64 + mi * 16 + lm) * 72 + ks + g * 8];
#pragma unroll
            for (int ni = 0; ni < 4; ++ni)
                bfr[ni] = *(const short8*)&Bsm[(wc * 64 + ni * 16 + lm) * 72 + ks + g * 8];
#pragma unroll
            for (int mi = 0; mi < 4; ++mi)
#pragma unroll
                for (int ni = 0; ni < 4; ++ni)
                    acc[mi][ni] = __builtin_amdgcn_mfma_f32_16x16x32_bf16(
                        af[mi], bfr[ni], acc[mi][ni], 0, 0, 0);
        }
        __syncthreads();
    }
    float bb[4];
#pragma unroll
    for (int ni = 0; ni < 4; ++ni)
        bb[ni] = bo[n0 + wc * 64 + ni * 16 + lm];
#pragma unroll
    for (int mi = 0; mi < 4; ++mi)
#pragma unroll
        for (int ni = 0; ni < 4; ++ni)
#pragma unroll
            for (int r = 0; r < 4; ++r) {
                int rowg = m0 + wr * 64 + mi * 16 + g * 4 + r;
                int colg = n0 + wc * 64 + ni * 16 + lm;
                out[(size_t)rowg * 1024 + colg] = acc[mi][ni][r] + bb[ni];
            }
}

// ---------------------------------------------------------------------------
// Flash attention v7: KVBLK=128 per stage (2x64-key subtiles), double-buffered
// LDS filled by global_load_lds (pre-swizzled source, zero ds_writes, zero
// staging VGPRs), ONE __syncthreads per 128 keys. QBLK=32 q-rows per wave.
//   S^T = mfma(K_frag, Q_frag): C rows = keys kb*16+g*4+r, cols = q lm.
//   PV: permuted Vt layout makes the B-operand one b128 read.
// ---------------------------------------------------------------------------
__global__ __launch_bounds__(256) void attn_kernel(
    const unsigned short* __restrict__ Q, const unsigned short* __restrict__ K,
    const unsigned short* __restrict__ VT, unsigned short* __restrict__ CTX) {
    __shared__ __align__(16) unsigned short Ksm[2][128 * 64];   // rows = keys
    __shared__ __align__(16) unsigned short Vtsm[2][128 * 64];  // row = s*64 + feature d

    const int tid = threadIdx.x;
    const int lane = tid & 63;
    const int w = tid >> 6;
    const int g = lane >> 4;
    const int lm = lane & 15;
    const int bh = blockIdx.x;
    const int qt = blockIdx.y;
    const int b = bh >> 4;
    const int h = bh & 15;

    const size_t base = (size_t)b * SEQ * D_MODEL + (size_t)h * DK;
    const size_t vtbase = (size_t)(h * 64) * NTOK + (size_t)b * SEQ;
    const int rs = (lm & 7) << 3;
    const int lr = lane >> 3;
    const int lc = lane & 7;

    // Q fragments (B-operand for S^T), prescaled by 1/8; 2 q-subtiles
    short8 qf[2][2];
#pragma unroll
    for (int qs = 0; qs < 2; ++qs) {
        const int qrow = qt * 128 + w * 32 + qs * 16 + lm;
#pragma unroll
        for (int t = 0; t < 2; ++t) {
            short8 raw = *(const short8*)&Q[base + (size_t)qrow * D_MODEL + t * 32 + g * 8];
            union { unsigned u[4]; short8 s; } r;
#pragma unroll
            for (int j = 0; j < 4; ++j) {
                float lo = bf2f((unsigned short)raw[2 * j]) * 0.125f;
                float hi = bf2f((unsigned short)raw[2 * j + 1]) * 0.125f;
                r.u[j] = pk2(lo, hi);
            }
            qf[qs][t] = r.s;
        }
    }

    float lsum[2] = {0.f, 0.f};
    floatx4 Oacc[2][4];
#pragma unroll
    for (int qs = 0; qs < 2; ++qs)
#pragma unroll
        for (int nb = 0; nb < 4; ++nb) Oacc[qs][nb] = (floatx4){0.f, 0.f, 0.f, 0.f};

    // stage a 128-key pair-tile into buffer p: wave w fills LDS rows [w*32,w*32+32)
    auto issue_pair = [&](int pr, int p) {
        const int krow0 = pr * 128;
#pragma unroll
        for (int i = 0; i < 4; ++i) {
            const int r0 = w * 32 + i * 8;
            const int row = r0 + lr;
            const int gcol = (lc ^ (row & 7)) << 3;
            glds16(&K[base + (size_t)(krow0 + row) * D_MODEL + gcol], &Ksm[p][r0 * 64]);
            glds16(&VT[vtbase + (size_t)(row & 63) * NTOK + krow0 + (row >> 6) * 64 + gcol],
                   &Vtsm[p][r0 * 64]);
        }
    };

    const int NP = SEQ / 128;   // 16
    issue_pair(0, 0);
    for (int pr = 0; pr < NP; ++pr) {
        const int p = pr & 1;
        __syncthreads();                     // vmcnt drain: pair pr staged, all waves
        if (pr + 1 < NP) issue_pair(pr + 1, p ^ 1);   // lands during compute below

#pragma unroll
        for (int s = 0; s < 2; ++s) {
            const unsigned short* Kt = &Ksm[p][s * 4096];
            const unsigned short* Vv = &Vtsm[p][s * 4096];

            // ---- S^T = K Q^T / 8 : per kb, rows = keys kb*16+g*4+r, col q=lm
            float pa[2][4][4];
#pragma unroll
            for (int kb = 0; kb < 4; ++kb) {
                short8 ak0 = *(const short8*)&Kt[(kb * 16 + lm) * 64 + ((0 + g * 8) ^ rs)];
                short8 ak1 = *(const short8*)&Kt[(kb * 16 + lm) * 64 + ((32 + g * 8) ^ rs)];
#pragma unroll
                for (int qs = 0; qs < 2; ++qs) {
                    floatx4 a = (floatx4){0.f, 0.f, 0.f, 0.f};
                    a = __builtin_amdgcn_mfma_f32_16x16x32_bf16(ak0, qf[qs][0], a, 0, 0, 0);
                    a = __builtin_amdgcn_mfma_f32_16x16x32_bf16(ak1, qf[qs][1], a, 0, 0, 0);
#pragma unroll
                    for (int r = 0; r < 4; ++r) pa[qs][kb][r] = __expf(a[r]);
                    lsum[qs] += (pa[qs][kb][0] + pa[qs][kb][1]) +
                                (pa[qs][kb][2] + pa[qs][kb][3]);
                }
            }

            // ---- O += P V : Vt fragment read once (b128), feeds both subtiles
#pragma unroll
            for (int cp = 0; cp < 2; ++cp) {
                const int c0 = 2 * cp, c1 = 2 * cp + 1;
                union { unsigned u[4]; short8 s; } ap[2];
#pragma unroll
                for (int qs = 0; qs < 2; ++qs) {
                    ap[qs].u[0] = pk2(pa[qs][c0][0], pa[qs][c0][1]);
                    ap[qs].u[1] = pk2(pa[qs][c0][2], pa[qs][c0][3]);
                    ap[qs].u[2] = pk2(pa[qs][c1][0], pa[qs][c1][1]);
                    ap[qs].u[3] = pk2(pa[qs][c1][2], pa[qs][c1][3]);
                }
#pragma unroll
                for (int nb = 0; nb < 4; ++nb) {
                    const int d = nb * 16 + lm;
                    short8 bv = *(const short8*)&Vv[d * 64 + ((g * 16 + cp * 8) ^ rs)];
                    Oacc[0][nb] = __builtin_amdgcn_mfma_f32_16x16x32_bf16(
                        ap[0].s, bv, Oacc[0][nb], 0, 0, 0);
                    Oacc[1][nb] = __builtin_amdgcn_mfma_f32_16x16x32_bf16(
                        ap[1].s, bv, Oacc[1][nb], 0, 0, 0);
                }
            }
        }
    }

    // ---- softmax denominator: reduce over g, redistribute to rows ----
#pragma unroll
    for (int qs = 0; qs < 2; ++qs) {
        float l = lsum[qs];
        l += __shfl_xor(l, 16, 64);
        l += __shfl_xor(l, 32, 64);   // all lanes: full l for q = w*32+qs*16+lm
        float lr4[4];
#pragma unroll
        for (int r = 0; r < 4; ++r)
            lr4[r] = __shfl(l, g * 4 + r, 64);   // l for q-row = ...+g*4+r
#pragma unroll
        for (int nb = 0; nb < 4; ++nb) {
#pragma unroll
            for (int r = 0; r < 4; ++r) {
                float val = Oacc[qs][nb][r] / lr4[r];
                int srow = qt * 128 + w * 32 + qs * 16 + g * 4 + r;
                CTX[base + (size_t)srow * D_MODEL + nb * 16 + lm] = f2bf(val);
            }
        }
    }
}

extern "C" void kernel_launch(void* const* d_in, const int* in_sizes, int n_in,
                              void* d_out, int out_size, void* d_ws, size_t ws_size,
                              hipStream_t stream) {
    const float* xq = (const float*)d_in[0];
    const float* xk = (const float*)d_in[1];
    const float* xv = (const float*)d_in[2];
    const float* wq = (const float*)d_in[3];
    const float* bq = (const float*)d_in[4];
    const float* wk = (const float*)d_in[5];
    const float* bk = (const float*)d_in[6];
    const float* wv = (const float*)d_in[7];
    const float* bv = (const float*)d_in[8];
    const float* wo = (const float*)d_in[9];
    const float* bo = (const float*)d_in[10];
    float* out = (float*)d_out;

    unsigned short* ws = (unsigned short*)d_ws;

    if (ws_size >= (size_t)68 * 1024 * 1024) {
        // bf16 path: Xb[3*MAT] | Wb[4*WMAT] | Q | K | VT | C
        unsigned short* Xb = ws;
        unsigned short* Wb = ws + (size_t)3 * MAT;
        unsigned short* Qw = Wb + (size_t)4 * WMAT;
        unsigned short* Kw = Qw + (size_t)MAT;
        unsigned short* VTw = Kw + (size_t)MAT;
        unsigned short* Cw = VTw + (size_t)MAT;

        cvt7<<<dim3(2048, 7), 256, 0, stream>>>(xq, xk, xv, wq, wk, wv, wo, ws);
        qkv_gemm_b<<<dim3(8, 32, 2), 256, 0, stream>>>(Xb, Wb, bq, bk, Qw);
        vt_gemm_b<<<dim3(32, 16), 256, 0, stream>>>(
            Wb + (size_t)2 * WMAT, Xb + (size_t)2 * MAT, bv, VTw);
        attn_kernel<<<dim3(2 * NH, SEQ / 128), 256, 0, stream>>>(Qw, Kw, VTw, Cw);
        out_gemm_b<<<dim3(8, 64), 256, 0, stream>>>(Cw, Wb + (size_t)3 * WMAT, bo, out);
    } else {
        unsigned short* Qw = ws;
        unsigned short* Kw = ws + (size_t)MAT;
        unsigned short* VTw = ws + (size_t)2 * MAT;
        unsigned short* Cw = ws + (size_t)3 * MAT;
        qkv_gemm_f<<<dim3(8, 32, 2), 256, 0, stream>>>(xq, xk, wq, wk, bq, bk, Qw, Kw);
        vt_gemm_f<<<dim3(32, 8), 256, 0, stream>>>(wv, xv, bv, VTw);
        attn_kernel<<<dim3(2 * NH, SEQ / 128), 256, 0, stream>>>(Qw, Kw, VTw, Cw);
        out_gemm_f<<<dim3(8, 32), 256, 0, stream>>>(wo, bo, Cw, out);
    }
}

// Round 5
// 229.684 us; speedup vs baseline: 1.1622x; 1.0230x over previous
//
#include <hip/hip_runtime.h>
#include <hip/hip_bf16.h>

// MultiheadAttention: B=2, S=2048, D=1024, H=16, dk=64.
// Inputs fp32, output fp32. Internals bf16 MFMA.
// V is produced TRANSPOSED ([feature][token]) by its projection GEMM, with
// tokens PERMUTED within each 64-token tile (t=c*16+g*4+e -> g*16+c*4+e) so
// the attention PV B-operand is a single contiguous b128 LDS read.
// All LDS tiles: stride-64 rows, XOR swizzle col ^= ((row&7)<<3) (16B granule).
// Staging: global_load_lds width=16 with PRE-SWIZZLED GLOBAL SOURCE (linear
// LDS dest + inverse-swizzled source + swizzled read). Double-buffered LDS,
// ONE __syncthreads per tile; prefetch issued post-barrier lands during compute.
// Attention VALU diet: exp2 via __builtin_amdgcn_exp2f with log2e folded into
// the Q prescale (kills the per-score v_mul), softmax denominator via an
// extra PV MFMA with B=ones (kills 32 VALU adds/subtile + epilogue
// shuffle-reduce), s_setprio(1) around MFMA clusters.

typedef __attribute__((ext_vector_type(8))) short short8;   // 8 bf16 = 4 VGPR (MFMA A/B frag)
typedef __attribute__((ext_vector_type(4))) float floatx4;  // MFMA C/D frag

#define D_MODEL 1024
#define SEQ 2048
#define NTOK 4096      // B*S
#define DK 64
#define NH 16
#define MAT 4194304    // NTOK*D_MODEL
#define WMAT 1048576   // D_MODEL*D_MODEL

static __device__ __forceinline__ unsigned short f2bf(float f) {
    unsigned int x = __float_as_uint(f);
    unsigned int r = x + 0x7fffu + ((x >> 16) & 1u);   // RNE
    return (unsigned short)(r >> 16);
}
static __device__ __forceinline__ float bf2f(unsigned short u) {
    return __uint_as_float(((unsigned int)u) << 16);
}
static __device__ __forceinline__ unsigned pk2(float x, float y) {
    __hip_bfloat162 h = __float22bfloat162_rn(make_float2(x, y));
    return *reinterpret_cast<unsigned*>(&h);
}
static __device__ __forceinline__ short8 cvt8(float4 f0, float4 f1) {
    union { unsigned u[4]; short8 s; } r;
    r.u[0] = pk2(f0.x, f0.y); r.u[1] = pk2(f0.z, f0.w);
    r.u[2] = pk2(f1.x, f1.y); r.u[3] = pk2(f1.z, f1.w);
    return r.s;
}
// token permutation within a 64-token tile: t=c*16+g*4+e -> g*16+c*4+e
static __device__ __forceinline__ int permtok(int t) {
    return ((t >> 2) & 3) * 16 + ((t >> 4) & 3) * 4 + (t & 3);
}
// async global->LDS, 16B per lane; LDS dest = wave-uniform base + lane*16
static __device__ __forceinline__ void glds16(const unsigned short* g, unsigned short* l) {
    __builtin_amdgcn_global_load_lds(
        (const __attribute__((address_space(1))) void*)g,
        (__attribute__((address_space(3))) void*)l, 16, 0, 0);
}

// ---------------------------------------------------------------------------
// fp32 -> bf16 conversion pass: xq,xk,xv (4M each) + wq,wk,wv,wo (1M each)
// ---------------------------------------------------------------------------
__global__ __launch_bounds__(256) void cvt7(
    const float* __restrict__ s0, const float* __restrict__ s1,
    const float* __restrict__ s2, const float* __restrict__ s3,
    const float* __restrict__ s4, const float* __restrict__ s5,
    const float* __restrict__ s6, unsigned short* __restrict__ dst) {
    const float* s; size_t doff; int n;
    switch (blockIdx.y) {
        case 0: s = s0; doff = 0;                          n = MAT;  break;
        case 1: s = s1; doff = (size_t)MAT;                n = MAT;  break;
        case 2: s = s2; doff = (size_t)2 * MAT;            n = MAT;  break;
        case 3: s = s3; doff = (size_t)3 * MAT;            n = WMAT; break;
        case 4: s = s4; doff = (size_t)3 * MAT + WMAT;     n = WMAT; break;
        case 5: s = s5; doff = (size_t)3 * MAT + 2 * WMAT; n = WMAT; break;
        default: s = s6; doff = (size_t)3 * MAT + 3 * WMAT; n = WMAT; break;
    }
    int idx = (blockIdx.x * 256 + threadIdx.x) * 8;
    if (idx >= n) return;
    float4 a = *(const float4*)(s + idx);
    float4 b = *(const float4*)(s + idx + 4);
    *(short8*)&dst[doff + idx] = cvt8(a, b);
}

// ---------------------------------------------------------------------------
// BMx128 NT GEMM, bf16 operands: out[m,n] = sum_k X[m,k]*W[n,k] + bias
// Double-buffered LDS, global_load_lds staging (pre-swizzled source), one
// __syncthreads per k-step with prefetch issued post-barrier.
// ---------------------------------------------------------------------------
template <bool F32OUT, bool ROWBIAS, bool PERMN, int OSTRIDE, int BM>
static __device__ __forceinline__ void gemm_bb(const unsigned short* __restrict__ X,
                                               const unsigned short* __restrict__ W,
                                               const float* __restrict__ bias,
                                               void* __restrict__ outp) {
    __shared__ __align__(16) unsigned short Asm[2][BM * 64];
    __shared__ __align__(16) unsigned short Bsm[2][128 * 64];
    constexpr int MF = BM / 32;          // m-fragments per wave
    constexpr int HALF = BM / 2;

    const int tid = threadIdx.x;
    const int lane = tid & 63;
    const int wv = tid >> 6;
    const int g = lane >> 4;
    const int lm = lane & 15;
    const int wr = wv >> 1;
    const int wc = wv & 1;
    const int m0 = blockIdx.y * BM;
    const int n0 = blockIdx.x * 128;
    const int rs = (lm & 7) << 3;          // read-side swizzle
    const int lr = lane >> 3;              // 0..7 : row within a glds group
    const int lc = lane & 7;               // 16B slot within row

    auto issue = [&](int k0, int p) {
#pragma unroll
        for (int i = 0; i < BM / 32; ++i) {
            const int r0 = wv * (BM / 4) + i * 8;
            const int row = r0 + lr;
            const int gcol = (lc ^ (row & 7)) << 3;
            glds16(&X[(size_t)(m0 + row) * 1024 + k0 + gcol], &Asm[p][r0 * 64]);
        }
#pragma unroll
        for (int i = 0; i < 4; ++i) {
            const int r0 = wv * 32 + i * 8;
            const int row = r0 + lr;
            const int gcol = (lc ^ (row & 7)) << 3;
            glds16(&W[(size_t)(n0 + row) * 1024 + k0 + gcol], &Bsm[p][r0 * 64]);
        }
    };

    floatx4 acc[MF][4];
#pragma unroll
    for (int mi = 0; mi < MF; ++mi)
#pragma unroll
        for (int ni = 0; ni < 4; ++ni)
            acc[mi][ni] = (floatx4){0.f, 0.f, 0.f, 0.f};

    issue(0, 0);
    for (int k0 = 0, it = 0; k0 < 1024; k0 += 64, ++it) {
        const int p = it & 1;
        __syncthreads();                         // vmcnt drain: tile it in LDS, all waves
        if (k0 + 64 < 1024) issue(k0 + 64, p ^ 1);   // prefetch lands during compute
#pragma unroll
        for (int ks = 0; ks < 64; ks += 32) {
            short8 af[MF], bfr[4];
#pragma unroll
            for (int mi = 0; mi < MF; ++mi)
                af[mi] = *(const short8*)&Asm[p][(wr * HALF + mi * 16 + lm) * 64 +
                                                ((ks + g * 8) ^ rs)];
#pragma unroll
            for (int ni = 0; ni < 4; ++ni)
                bfr[ni] = *(const short8*)&Bsm[p][(wc * 64 + ni * 16 + lm) * 64 +
                                                 ((ks + g * 8) ^ rs)];
#pragma unroll
            for (int mi = 0; mi < MF; ++mi)
#pragma unroll
                for (int ni = 0; ni < 4; ++ni)
                    acc[mi][ni] = __builtin_amdgcn_mfma_f32_16x16x32_bf16(
                        af[mi], bfr[ni], acc[mi][ni], 0, 0, 0);
        }
    }

    float cb[4];
#pragma unroll
    for (int ni = 0; ni < 4; ++ni)
        cb[ni] = ROWBIAS ? 0.f : bias[n0 + wc * 64 + ni * 16 + lm];
#pragma unroll
    for (int mi = 0; mi < MF; ++mi)
#pragma unroll
        for (int r = 0; r < 4; ++r) {
            int rowg = m0 + wr * HALF + mi * 16 + g * 4 + r;
            float rb = ROWBIAS ? bias[rowg] : 0.f;
#pragma unroll
            for (int ni = 0; ni < 4; ++ni) {
                int colg = n0 + wc * 64 + ni * 16 + lm;
                if (PERMN) colg = (colg & ~63) | permtok(colg & 63);
                float val = acc[mi][ni][r] + (ROWBIAS ? rb : cb[ni]);
                if (F32OUT)
                    ((float*)outp)[(size_t)rowg * OSTRIDE + colg] = val;
                else
                    ((unsigned short*)outp)[(size_t)rowg * OSTRIDE + colg] = f2bf(val);
            }
        }
}

__global__ __launch_bounds__(256) void qkv_gemm_b(
    const unsigned short* __restrict__ Xb, const unsigned short* __restrict__ Wb,
    const float* __restrict__ bq, const float* __restrict__ bk,
    unsigned short* __restrict__ QK) {
    const int z = blockIdx.z;                    // 0 = Q, 1 = K
    const float* bias = (z == 0) ? bq : bk;
    gemm_bb<false, false, false, 1024, 128>(Xb + (size_t)z * MAT, Wb + (size_t)z * WMAT,
                                            bias, QK + (size_t)z * MAT);
}

// V^T projection: out[m=feature][n=token(permuted)] = sum_k Wv[m,k]*Xv[n,k] + bv[m]
__global__ __launch_bounds__(256) void vt_gemm_b(
    const unsigned short* __restrict__ Wv, const unsigned short* __restrict__ Xv,
    const float* __restrict__ bv, unsigned short* __restrict__ VT) {
    gemm_bb<false, true, true, 4096, 64>(Wv, Xv, bv, VT);
}

__global__ __launch_bounds__(256) void out_gemm_b(
    const unsigned short* __restrict__ ctx, const unsigned short* __restrict__ Wo,
    const float* __restrict__ bo, float* __restrict__ out) {
    gemm_bb<true, false, false, 1024, 64>(ctx, Wo, bo, out);
}

// ---------------- fallback path (fp32 staging), used if ws too small --------
template <bool ROWBIAS, bool PERMN, int OSTRIDE>
static __device__ __forceinline__ void gemm128_f(const float* __restrict__ X,
                                                 const float* __restrict__ W,
                                                 const float* __restrict__ bias,
                                                 unsigned short* __restrict__ out) {
    __shared__ __align__(16) unsigned short Asm[128 * 72];
    __shared__ __align__(16) unsigned short Bsm[128 * 72];
    const int tid = threadIdx.x;
    const int lane = tid & 63;
    const int wv = tid >> 6;
    const int g = lane >> 4;
    const int lm = lane & 15;
    const int wr = wv >> 1;
    const int wc = wv & 1;
    const int m0 = blockIdx.y * 128;
    const int n0 = blockIdx.x * 128;
    floatx4 acc[4][4];
#pragma unroll
    for (int mi = 0; mi < 4; ++mi)
#pragma unroll
        for (int ni = 0; ni < 4; ++ni)
            acc[mi][ni] = (floatx4){0.f, 0.f, 0.f, 0.f};
    for (int k0 = 0; k0 < 1024; k0 += 64) {
#pragma unroll
        for (int i = 0; i < 4; ++i) {
            int idx = tid + i * 256;
            int row = idx >> 3;
            int col = (idx & 7) << 3;
            const float* sa = &X[(size_t)(m0 + row) * 1024 + k0 + col];
            *(short8*)&Asm[row * 72 + col] = cvt8(*(const float4*)sa, *(const float4*)(sa + 4));
            const float* sb = &W[(size_t)(n0 + row) * 1024 + k0 + col];
            *(short8*)&Bsm[row * 72 + col] = cvt8(*(const float4*)sb, *(const float4*)(sb + 4));
        }
        __syncthreads();
#pragma unroll
        for (int ks = 0; ks < 64; ks += 32) {
            short8 af[4], bfr[4];
#pragma unroll
            for (int mi = 0; mi < 4; ++mi)
                af[mi] = *(const short8*)&Asm[(wr * 64 + mi * 16 + lm) * 72 + ks + g * 8];
#pragma unroll
            for (int ni = 0; ni < 4; ++ni)
                bfr[ni] = *(const short8*)&Bsm[(wc * 64 + ni * 16 + lm) * 72 + ks + g * 8];
#pragma unroll
            for (int mi = 0; mi < 4; ++mi)
#pragma unroll
                for (int ni = 0; ni < 4; ++ni)
                    acc[mi][ni] = __builtin_amdgcn_mfma_f32_16x16x32_bf16(
                        af[mi], bfr[ni], acc[mi][ni], 0, 0, 0);
        }
        __syncthreads();
    }
    float cb[4];
#pragma unroll
    for (int ni = 0; ni < 4; ++ni)
        cb[ni] = ROWBIAS ? 0.f : bias[n0 + wc * 64 + ni * 16 + lm];
#pragma unroll
    for (int mi = 0; mi < 4; ++mi)
#pragma unroll
        for (int r = 0; r < 4; ++r) {
            int rowg = m0 + wr * 64 + mi * 16 + g * 4 + r;
            float rb = ROWBIAS ? bias[rowg] : 0.f;
#pragma unroll
            for (int ni = 0; ni < 4; ++ni) {
                int colg = n0 + wc * 64 + ni * 16 + lm;
                if (PERMN) colg = (colg & ~63) | permtok(colg & 63);
                out[(size_t)rowg * OSTRIDE + colg] =
                    f2bf(acc[mi][ni][r] + (ROWBIAS ? rb : cb[ni]));
            }
        }
}

__global__ __launch_bounds__(256) void qkv_gemm_f(
    const float* __restrict__ xq, const float* __restrict__ xk,
    const float* __restrict__ wq, const float* __restrict__ wk,
    const float* __restrict__ bq, const float* __restrict__ bk,
    unsigned short* __restrict__ q, unsigned short* __restrict__ k) {
    if (blockIdx.z == 0) gemm128_f<false, false, 1024>(xq, wq, bq, q);
    else                 gemm128_f<false, false, 1024>(xk, wk, bk, k);
}

__global__ __launch_bounds__(256) void vt_gemm_f(
    const float* __restrict__ wv, const float* __restrict__ xv,
    const float* __restrict__ bv, unsigned short* __restrict__ VT) {
    gemm128_f<true, true, 4096>(wv, xv, bv, VT);
}

__global__ __launch_bounds__(256) void out_gemm_f(
    const float* __restrict__ wo, const float* __restrict__ bo,
    const unsigned short* __restrict__ ctx, float* __restrict__ out) {
    __shared__ __align__(16) unsigned short Asm[128 * 72];
    __shared__ __align__(16) unsigned short Bsm[128 * 72];
    const int tid = threadIdx.x;
    const int lane = tid & 63;
    const int wv = tid >> 6;
    const int g = lane >> 4;
    const int lm = lane & 15;
    const int wr = wv >> 1;
    const int wc = wv & 1;
    const int m0 = blockIdx.y * 128;
    const int n0 = blockIdx.x * 128;
    floatx4 acc[4][4];
#pragma unroll
    for (int mi = 0; mi < 4; ++mi)
#pragma unroll
        for (int ni = 0; ni < 4; ++ni)
            acc[mi][ni] = (floatx4){0.f, 0.f, 0.f, 0.f};
    for (int k0 = 0; k0 < 1024; k0 += 64) {
#pragma unroll
        for (int i = 0; i < 4; ++i) {
            int idx = tid + i * 256;
            int row = idx >> 3;
            int col = (idx & 7) << 3;
            *(uint4*)&Asm[row * 72 + col] =
                *(const uint4*)&ctx[(size_t)(m0 + row) * 1024 + k0 + col];
            const float* sb = &wo[(size_t)(n0 + row) * 1024 + k0 + col];
            *(short8*)&Bsm[row * 72 + col] = cvt8(*(const float4*)sb, *(const float4*)(sb + 4));
        }
        __syncthreads();
#pragma unroll
        for (int ks = 0; ks < 64; ks += 32) {
            short8 af[4], bfr[4];
#pragma unroll
            for (int mi = 0; mi < 4; ++mi)
                af[mi] = *(const short8*)&Asm[(wr * 64 + mi * 16 + lm) * 72 + ks + g * 8];
#pragma unroll
            for (int ni = 0; ni < 4; ++ni)
                bfr[ni] = *(const short8*)&Bsm[(wc * 64 + ni * 16 + lm) * 72 + ks + g * 8];
#pragma unroll
            for (int mi = 0; mi < 4; ++mi)
#pragma unroll
                for (int ni = 0; ni < 4; ++ni)
                    acc[mi][ni] = __builtin_amdgcn_mfma_f32_16x16x32_bf16(
                        af[mi], bfr[ni], acc[mi][ni], 0, 0, 0);
        }
        __syncthreads();
    }
    float bb[4];
#pragma unroll
    for (int ni = 0; ni < 4; ++ni)
        bb[ni] = bo[n0 + wc * 64 + ni * 16 + lm];
#pragma unroll
    for (int mi = 0; mi < 4; ++mi)
#pragma unroll
        for (int ni = 0; ni < 4; ++ni)
#pragma unroll
            for (int r = 0; r < 4; ++r) {
                int rowg = m0 + wr * 64 + mi * 16 + g * 4 + r;
                int colg = n0 + wc * 64 + ni * 16 + lm;
                out[(size_t)rowg * 1024 + colg] = acc[mi][ni][r] + bb[ni];
            }
}

// ---------------------------------------------------------------------------
// Flash attention v8: v7 structure + VALU diet.
//   - Q prescaled by log2(e)/8; scores exponentiated with v_exp_f32 (2^x)
//     via __builtin_amdgcn_exp2f -> no per-score multiply.
//   - Softmax denominator via extra PV MFMA with B = ones (bf16 1.0): output
//     C row = q-row, all cols identical -> l lands per-lane in Lacc[r] with
//     the exact Oacc layout; no VALU adds, no epilogue shuffle-reduce.
//   - s_setprio(1) around MFMA clusters (independent blocks per CU -> waves
//     at different phases; scheduler favors the MFMA-issuing wave).
// ---------------------------------------------------------------------------
__global__ __launch_bounds__(256) void attn_kernel(
    const unsigned short* __restrict__ Q, const unsigned short* __restrict__ K,
    const unsigned short* __restrict__ VT, unsigned short* __restrict__ CTX) {
    __shared__ __align__(16) unsigned short Ksm[2][128 * 64];   // rows = keys
    __shared__ __align__(16) unsigned short Vtsm[2][128 * 64];  // row = s*64 + feature d

    const int tid = threadIdx.x;
    const int lane = tid & 63;
    const int w = tid >> 6;
    const int g = lane >> 4;
    const int lm = lane & 15;
    const int bh = blockIdx.x;
    const int qt = blockIdx.y;
    const int b = bh >> 4;
    const int h = bh & 15;

    const size_t base = (size_t)b * SEQ * D_MODEL + (size_t)h * DK;
    const size_t vtbase = (size_t)(h * 64) * NTOK + (size_t)b * SEQ;
    const int rs = (lm & 7) << 3;
    const int lr = lane >> 3;
    const int lc = lane & 7;

    // ones vector (bf16 1.0 x8) for the denominator MFMA
    union { unsigned u[4]; short8 s; } onev;
    onev.u[0] = 0x3F803F80u; onev.u[1] = 0x3F803F80u;
    onev.u[2] = 0x3F803F80u; onev.u[3] = 0x3F803F80u;

    // Q fragments (B-operand for S^T), prescaled by log2(e)/8; 2 q-subtiles
    short8 qf[2][2];
#pragma unroll
    for (int qs = 0; qs < 2; ++qs) {
        const int qrow = qt * 128 + w * 32 + qs * 16 + lm;
#pragma unroll
        for (int t = 0; t < 2; ++t) {
            short8 raw = *(const short8*)&Q[base + (size_t)qrow * D_MODEL + t * 32 + g * 8];
            union { unsigned u[4]; short8 s; } r;
#pragma unroll
            for (int j = 0; j < 4; ++j) {
                float lo = bf2f((unsigned short)raw[2 * j]) * 0.1803368801f;
                float hi = bf2f((unsigned short)raw[2 * j + 1]) * 0.1803368801f;
                r.u[j] = pk2(lo, hi);
            }
            qf[qs][t] = r.s;
        }
    }

    floatx4 Oacc[2][4];
    floatx4 Lacc[2];
#pragma unroll
    for (int qs = 0; qs < 2; ++qs) {
        Lacc[qs] = (floatx4){0.f, 0.f, 0.f, 0.f};
#pragma unroll
        for (int nb = 0; nb < 4; ++nb) Oacc[qs][nb] = (floatx4){0.f, 0.f, 0.f, 0.f};
    }

    // stage a 128-key pair-tile into buffer p: wave w fills LDS rows [w*32,w*32+32)
    auto issue_pair = [&](int pr, int p) {
        const int krow0 = pr * 128;
#pragma unroll
        for (int i = 0; i < 4; ++i) {
            const int r0 = w * 32 + i * 8;
            const int row = r0 + lr;
            const int gcol = (lc ^ (row & 7)) << 3;
            glds16(&K[base + (size_t)(krow0 + row) * D_MODEL + gcol], &Ksm[p][r0 * 64]);
            glds16(&VT[vtbase + (size_t)(row & 63) * NTOK + krow0 + (row >> 6) * 64 + gcol],
                   &Vtsm[p][r0 * 64]);
        }
    };

    const int NP = SEQ / 128;   // 16
    issue_pair(0, 0);
    for (int pr = 0; pr < NP; ++pr) {
        const int p = pr & 1;
        __syncthreads();                     // vmcnt drain: pair pr staged, all waves
        if (pr + 1 < NP) issue_pair(pr + 1, p ^ 1);   // lands during compute below

#pragma unroll
        for (int s = 0; s < 2; ++s) {
            const unsigned short* Kt = &Ksm[p][s * 4096];
            const unsigned short* Vv = &Vtsm[p][s * 4096];

            // ---- S^T = K Q^T * log2e/8 : rows = keys kb*16+g*4+r, col q=lm
            float pa[2][4][4];
#pragma unroll
            for (int kb = 0; kb < 4; ++kb) {
                short8 ak0 = *(const short8*)&Kt[(kb * 16 + lm) * 64 + ((0 + g * 8) ^ rs)];
                short8 ak1 = *(const short8*)&Kt[(kb * 16 + lm) * 64 + ((32 + g * 8) ^ rs)];
#pragma unroll
                for (int qs = 0; qs < 2; ++qs) {
                    floatx4 a = (floatx4){0.f, 0.f, 0.f, 0.f};
                    __builtin_amdgcn_s_setprio(1);
                    a = __builtin_amdgcn_mfma_f32_16x16x32_bf16(ak0, qf[qs][0], a, 0, 0, 0);
                    a = __builtin_amdgcn_mfma_f32_16x16x32_bf16(ak1, qf[qs][1], a, 0, 0, 0);
                    __builtin_amdgcn_s_setprio(0);
#pragma unroll
                    for (int r = 0; r < 4; ++r) pa[qs][kb][r] = __builtin_amdgcn_exp2f(a[r]);
                }
            }

            // ---- O += P V ; l += P * ones : Vt fragment read once (b128)
#pragma unroll
            for (int cp = 0; cp < 2; ++cp) {
                const int c0 = 2 * cp, c1 = 2 * cp + 1;
                union { unsigned u[4]; short8 s; } ap[2];
#pragma unroll
                for (int qs = 0; qs < 2; ++qs) {
                    ap[qs].u[0] = pk2(pa[qs][c0][0], pa[qs][c0][1]);
                    ap[qs].u[1] = pk2(pa[qs][c0][2], pa[qs][c0][3]);
                    ap[qs].u[2] = pk2(pa[qs][c1][0], pa[qs][c1][1]);
                    ap[qs].u[3] = pk2(pa[qs][c1][2], pa[qs][c1][3]);
                }
                __builtin_amdgcn_s_setprio(1);
#pragma unroll
                for (int nb = 0; nb < 4; ++nb) {
                    const int d = nb * 16 + lm;
                    short8 bv = *(const short8*)&Vv[d * 64 + ((g * 16 + cp * 8) ^ rs)];
                    Oacc[0][nb] = __builtin_amdgcn_mfma_f32_16x16x32_bf16(
                        ap[0].s, bv, Oacc[0][nb], 0, 0, 0);
                    Oacc[1][nb] = __builtin_amdgcn_mfma_f32_16x16x32_bf16(
                        ap[1].s, bv, Oacc[1][nb], 0, 0, 0);
                }
                Lacc[0] = __builtin_amdgcn_mfma_f32_16x16x32_bf16(
                    ap[0].s, onev.s, Lacc[0], 0, 0, 0);
                Lacc[1] = __builtin_amdgcn_mfma_f32_16x16x32_bf16(
                    ap[1].s, onev.s, Lacc[1], 0, 0, 0);
                __builtin_amdgcn_s_setprio(0);
            }
        }
    }

    // ---- normalize and store: l for q-row ...+g*4+r is Lacc[qs][r] (all cols) ----
#pragma unroll
    for (int qs = 0; qs < 2; ++qs) {
        float rl[4];
#pragma unroll
        for (int r = 0; r < 4; ++r) rl[r] = 1.0f / Lacc[qs][r];
#pragma unroll
        for (int nb = 0; nb < 4; ++nb) {
#pragma unroll
            for (int r = 0; r < 4; ++r) {
                float val = Oacc[qs][nb][r] * rl[r];
                int srow = qt * 128 + w * 32 + qs * 16 + g * 4 + r;
                CTX[base + (size_t)srow * D_MODEL + nb * 16 + lm] = f2bf(val);
            }
        }
    }
}

extern "C" void kernel_launch(void* const* d_in, const int* in_sizes, int n_in,
                              void* d_out, int out_size, void* d_ws, size_t ws_size,
                              hipStream_t stream) {
    const float* xq = (const float*)d_in[0];
    const float* xk = (const float*)d_in[1];
    const float* xv = (const float*)d_in[2];
    const float* wq = (const float*)d_in[3];
    const float* bq = (const float*)d_in[4];
    const float* wk = (const float*)d_in[5];
    const float* bk = (const float*)d_in[6];
    const float* wv = (const float*)d_in[7];
    const float* bv = (const float*)d_in[8];
    const float* wo = (const float*)d_in[9];
    const float* bo = (const float*)d_in[10];
    float* out = (float*)d_out;

    unsigned short* ws = (unsigned short*)d_ws;

    if (ws_size >= (size_t)68 * 1024 * 1024) {
        // bf16 path: Xb[3*MAT] | Wb[4*WMAT] | Q | K | VT | C
        unsigned short* Xb = ws;
        unsigned short* Wb = ws + (size_t)3 * MAT;
        unsigned short* Qw = Wb + (size_t)4 * WMAT;
        unsigned short* Kw = Qw + (size_t)MAT;
        unsigned short* VTw = Kw + (size_t)MAT;
        unsigned short* Cw = VTw + (size_t)MAT;

        cvt7<<<dim3(2048, 7), 256, 0, stream>>>(xq, xk, xv, wq, wk, wv, wo, ws);
        qkv_gemm_b<<<dim3(8, 32, 2), 256, 0, stream>>>(Xb, Wb, bq, bk, Qw);
        vt_gemm_b<<<dim3(32, 16), 256, 0, stream>>>(
            Wb + (size_t)2 * WMAT, Xb + (size_t)2 * MAT, bv, VTw);
        attn_kernel<<<dim3(2 * NH, SEQ / 128), 256, 0, stream>>>(Qw, Kw, VTw, Cw);
        out_gemm_b<<<dim3(8, 64), 256, 0, stream>>>(Cw, Wb + (size_t)3 * WMAT, bo, out);
    } else {
        unsigned short* Qw = ws;
        unsigned short* Kw = ws + (size_t)MAT;
        unsigned short* VTw = ws + (size_t)2 * MAT;
        unsigned short* Cw = ws + (size_t)3 * MAT;
        qkv_gemm_f<<<dim3(8, 32, 2), 256, 0, stream>>>(xq, xk, wq, wk, bq, bk, Qw, Kw);
        vt_gemm_f<<<dim3(32, 8), 256, 0, stream>>>(wv, xv, bv, VTw);
        attn_kernel<<<dim3(2 * NH, SEQ / 128), 256, 0, stream>>>(Qw, Kw, VTw, Cw);
        out_gemm_f<<<dim3(8, 32), 256, 0, stream>>>(wo, bo, Cw, out);
    }
}